// Round 1
// baseline (3498.576 us; speedup 1.0000x reference)
//
#include <hip/hip_runtime.h>
#include <hip/hip_bf16.h>

#define D 128
#define BM 64
#define BK 32

// ---------------- degree count ----------------
__global__ void degree_kernel(const int* __restrict__ src, const int* __restrict__ dst,
                              float* __restrict__ deg_out, float* __restrict__ deg_in, int E) {
    int i = blockIdx.x * blockDim.x + threadIdx.x;
    if (i < E) {
        atomicAdd(&deg_out[src[i]], 1.0f);
        atomicAdd(&deg_in[dst[i]], 1.0f);
    }
}

// ---------------- deg -> rsqrt(max(deg,1)) ----------------
__global__ void rsqrt_kernel(float* __restrict__ deg, int n) {
    int i = blockIdx.x * blockDim.x + threadIdx.x;
    if (i < n) deg[i] = rsqrtf(fmaxf(deg[i], 1.0f));
}

// ---------------- y = x @ W  (fp32, 64x128 tile, BK=32) ----------------
__global__ __launch_bounds__(256) void gemm_kernel(const float* __restrict__ x,
                                                   const float* __restrict__ W,
                                                   float* __restrict__ y, int nrows) {
    __shared__ float xs[BK][BM];   // transposed x tile: [k][row], 8 KB
    __shared__ float ws[BK][D];    // W tile: [k][col], 16 KB

    const int tid = threadIdx.x;
    const int tx = tid & 31;   // col group: cols tx*4 .. tx*4+3
    const int ty = tid >> 5;   // row group: rows ty*8 .. ty*8+7
    const int row0 = blockIdx.x * BM;

    float acc[8][4];
#pragma unroll
    for (int i = 0; i < 8; ++i)
#pragma unroll
        for (int j = 0; j < 4; ++j) acc[i][j] = 0.f;

    for (int kt = 0; kt < D; kt += BK) {
        __syncthreads();
        // stage x tile: 64 rows x 32 k = 512 float4; 2 per thread
#pragma unroll
        for (int l = 0; l < 2; ++l) {
            int idx = tid + l * 256;      // 0..511
            int r   = idx >> 3;           // row in tile (8 float4 per row)
            int k4  = idx & 7;
            float4 v = make_float4(0.f, 0.f, 0.f, 0.f);
            int grow = row0 + r;
            if (grow < nrows) v = *(const float4*)(x + (size_t)grow * D + kt + k4 * 4);
            xs[k4 * 4 + 0][r] = v.x;
            xs[k4 * 4 + 1][r] = v.y;
            xs[k4 * 4 + 2][r] = v.z;
            xs[k4 * 4 + 3][r] = v.w;
        }
        // stage W tile: 32 k x 128 cols = 1024 float4; 4 per thread
#pragma unroll
        for (int l = 0; l < 4; ++l) {
            int idx = tid + l * 256;      // 0..1023
            int kk  = idx >> 5;           // k row (32 float4 per k)
            int c4  = idx & 31;
            float4 v = *(const float4*)(W + (size_t)(kt + kk) * D + c4 * 4);
            *(float4*)&ws[kk][c4 * 4] = v;
        }
        __syncthreads();
#pragma unroll
        for (int k = 0; k < BK; ++k) {
            float4 wv = *(const float4*)&ws[k][tx * 4];
            float4 xa = *(const float4*)&xs[k][ty * 8];
            float4 xb = *(const float4*)&xs[k][ty * 8 + 4];
            float xv[8] = {xa.x, xa.y, xa.z, xa.w, xb.x, xb.y, xb.z, xb.w};
#pragma unroll
            for (int i = 0; i < 8; ++i) {
                acc[i][0] += xv[i] * wv.x;
                acc[i][1] += xv[i] * wv.y;
                acc[i][2] += xv[i] * wv.z;
                acc[i][3] += xv[i] * wv.w;
            }
        }
    }
#pragma unroll
    for (int i = 0; i < 8; ++i) {
        int grow = row0 + ty * 8 + i;
        if (grow < nrows)
            *(float4*)(y + (size_t)grow * D + tx * 4) =
                make_float4(acc[i][0], acc[i][1], acc[i][2], acc[i][3]);
    }
}

// ---------------- scatter: out[dst] += c * y[src], 32 lanes/edge ----------------
__global__ __launch_bounds__(256) void scatter_kernel(const float* __restrict__ y,
                                                      const int* __restrict__ src,
                                                      const int* __restrict__ dst,
                                                      const float* __restrict__ rs_out,
                                                      const float* __restrict__ rs_in,
                                                      float* __restrict__ out, int E) {
    int gid  = blockIdx.x * blockDim.x + threadIdx.x;
    int edge = gid >> 5;
    int lane = gid & 31;
    if (edge >= E) return;
    int s = src[edge];
    int d = dst[edge];
    float c = rs_out[s] * rs_in[d];
    float4 v = ((const float4*)(y + (size_t)s * D))[lane];
    float* orow = out + (size_t)d * D + lane * 4;
    atomicAdd(orow + 0, v.x * c);
    atomicAdd(orow + 1, v.y * c);
    atomicAdd(orow + 2, v.z * c);
    atomicAdd(orow + 3, v.w * c);
}

// ---------------- out = relu(out + b0+b1+b2), float4 ----------------
__global__ void finalize_kernel(float* __restrict__ out, const float* __restrict__ b0,
                                const float* __restrict__ b1, const float* __restrict__ b2,
                                int n4) {
    int i = blockIdx.x * blockDim.x + threadIdx.x;
    if (i >= n4) return;
    int c = (i & 31) * 4;
    float4 v = ((float4*)out)[i];
    v.x = fmaxf(v.x + b0[c + 0] + b1[c + 0] + b2[c + 0], 0.f);
    v.y = fmaxf(v.y + b0[c + 1] + b1[c + 1] + b2[c + 1], 0.f);
    v.z = fmaxf(v.z + b0[c + 2] + b1[c + 2] + b2[c + 2], 0.f);
    v.w = fmaxf(v.w + b0[c + 3] + b1[c + 3] + b2[c + 3], 0.f);
    ((float4*)out)[i] = v;
}

extern "C" void kernel_launch(void* const* d_in, const int* in_sizes, int n_in,
                              void* d_out, int out_size, void* d_ws, size_t ws_size,
                              hipStream_t stream) {
    // setup_inputs() dict order: x, then (W, b, src, dst) per relation
    const float* x = (const float*)d_in[0];
    const float* W[3]   = {(const float*)d_in[1], (const float*)d_in[5], (const float*)d_in[9]};
    const float* b[3]   = {(const float*)d_in[2], (const float*)d_in[6], (const float*)d_in[10]};
    const int*   src[3] = {(const int*)d_in[3],   (const int*)d_in[7],   (const int*)d_in[11]};
    const int*   dst[3] = {(const int*)d_in[4],   (const int*)d_in[8],   (const int*)d_in[12]};

    const int N = in_sizes[0] / D;
    const int E = in_sizes[3];
    float* out = (float*)d_out;

    // workspace layout: [deg_out0, deg_in0, deg_out1, deg_in1, deg_out2, deg_in2][y]
    float* ws_f = (float*)d_ws;
    float* deg[6];
    for (int i = 0; i < 6; ++i) deg[i] = ws_f + (size_t)i * N;
    float* y = ws_f + (size_t)6 * N;

    // zero accumulator (d_out) and degree arrays (both poisoned 0xAA)
    hipMemsetAsync(d_out, 0, (size_t)out_size * sizeof(float), stream);
    hipMemsetAsync(ws_f, 0, (size_t)6 * N * sizeof(float), stream);

    // degrees
    {
        int blocks = (E + 255) / 256;
        for (int r = 0; r < 3; ++r)
            degree_kernel<<<blocks, 256, 0, stream>>>(src[r], dst[r], deg[2 * r], deg[2 * r + 1], E);
        int n6 = 6 * N;
        rsqrt_kernel<<<(n6 + 255) / 256, 256, 0, stream>>>(ws_f, n6);
    }

    // per relation: GEMM then scatter (stream order serializes y reuse)
    {
        int gblocks = (N + BM - 1) / BM;
        int sblocks = (E * 32 + 255) / 256;
        for (int r = 0; r < 3; ++r) {
            gemm_kernel<<<gblocks, 256, 0, stream>>>(x, W[r], y, N);
            scatter_kernel<<<sblocks, 256, 0, stream>>>(y, src[r], dst[r], deg[2 * r],
                                                        deg[2 * r + 1], out, E);
        }
    }

    // bias + relu
    {
        int n4 = out_size / 4;
        finalize_kernel<<<(n4 + 255) / 256, 256, 0, stream>>>(out, b[0], b[1], b[2], n4);
    }
}

// Round 2
// 673.143 us; speedup vs baseline: 5.1974x; 5.1974x over previous
//
#include <hip/hip_runtime.h>
#include <hip/hip_bf16.h>

#define D 128
#define BM 64
#define BK 32

__device__ __forceinline__ float bf2f(unsigned short v) {
    union { unsigned int u; float f; } t;
    t.u = ((unsigned int)v) << 16;
    return t.f;
}

// ---------------- degree count (int atomics) ----------------
__global__ void degree_kernel(const int* __restrict__ src, const int* __restrict__ dst,
                              int* __restrict__ cnt_out, int* __restrict__ cnt_in, int E) {
    int i = blockIdx.x * blockDim.x + threadIdx.x;
    if (i < E) {
        atomicAdd(&cnt_out[src[i]], 1);
        atomicAdd(&cnt_in[dst[i]], 1);
    }
}

// ---------------- cnt(int) -> rsqrt(max(cnt,1)) ----------------
__global__ void rsqrt_kernel(const int* __restrict__ cnt, float* __restrict__ rs, int n) {
    int i = blockIdx.x * blockDim.x + threadIdx.x;
    if (i < n) rs[i] = rsqrtf(fmaxf((float)cnt[i], 1.0f));
}

// ---------------- exclusive scan: phase 1 (per-block) ----------------
__global__ void scan_block(const int* __restrict__ in, int* __restrict__ out,
                           int* __restrict__ aux, int n) {
    __shared__ int tmp[256];
    int tid = threadIdx.x;
    int gid = blockIdx.x * 256 + tid;
    int v = (gid < n) ? in[gid] : 0;
    tmp[tid] = v;
    __syncthreads();
    for (int o = 1; o < 256; o <<= 1) {
        int t = (tid >= o) ? tmp[tid - o] : 0;
        __syncthreads();
        tmp[tid] += t;
        __syncthreads();
    }
    if (gid < n) out[gid] = tmp[tid] - v;   // exclusive
    if (tid == 255) aux[blockIdx.x] = tmp[255];
}

// ---------------- scan phase 2 (aux, single block, nb <= 512) ----------------
__global__ void scan_aux(int* __restrict__ aux, int nb) {
    __shared__ int tmp[512];
    int tid = threadIdx.x;
    int v = (tid < nb) ? aux[tid] : 0;
    tmp[tid] = v;
    __syncthreads();
    for (int o = 1; o < 512; o <<= 1) {
        int t = (tid >= o) ? tmp[tid - o] : 0;
        __syncthreads();
        tmp[tid] += t;
        __syncthreads();
    }
    if (tid < nb) aux[tid] = tmp[tid] - v;  // exclusive
}

// ---------------- scan phase 3 (add block offsets) ----------------
__global__ void scan_add(int* __restrict__ out, const int* __restrict__ aux, int n) {
    int gid = blockIdx.x * 256 + threadIdx.x;
    if (gid < n) out[gid] += aux[blockIdx.x];
}

// ---------------- CSR fill: bucket src ids by dst ----------------
__global__ void fill_kernel(const int* __restrict__ src, const int* __restrict__ dst,
                            const int* __restrict__ off, int* __restrict__ cursor,
                            int* __restrict__ src_sorted, int E) {
    int e = blockIdx.x * blockDim.x + threadIdx.x;
    if (e >= E) return;
    int d = dst[e];
    int p = atomicAdd(&cursor[d], 1);
    src_sorted[off[d] + p] = src[e];
}

// ---------------- y = x @ W  (fp32 compute, bf16 store) ----------------
__global__ __launch_bounds__(256) void gemm_kernel(const float* __restrict__ x,
                                                   const float* __restrict__ W,
                                                   __hip_bfloat16* __restrict__ y, int nrows) {
    __shared__ float xs[BK][BM];   // transposed x tile
    __shared__ float ws[BK][D];    // W tile

    const int tid = threadIdx.x;
    const int tx = tid & 31;   // cols tx*4 .. tx*4+3
    const int ty = tid >> 5;   // rows ty*8 .. ty*8+7
    const int row0 = blockIdx.x * BM;

    float acc[8][4];
#pragma unroll
    for (int i = 0; i < 8; ++i)
#pragma unroll
        for (int j = 0; j < 4; ++j) acc[i][j] = 0.f;

    for (int kt = 0; kt < D; kt += BK) {
        __syncthreads();
#pragma unroll
        for (int l = 0; l < 2; ++l) {
            int idx = tid + l * 256;
            int r   = idx >> 3;
            int k4  = idx & 7;
            float4 v = make_float4(0.f, 0.f, 0.f, 0.f);
            int grow = row0 + r;
            if (grow < nrows) v = *(const float4*)(x + (size_t)grow * D + kt + k4 * 4);
            xs[k4 * 4 + 0][r] = v.x;
            xs[k4 * 4 + 1][r] = v.y;
            xs[k4 * 4 + 2][r] = v.z;
            xs[k4 * 4 + 3][r] = v.w;
        }
#pragma unroll
        for (int l = 0; l < 4; ++l) {
            int idx = tid + l * 256;
            int kk  = idx >> 5;
            int c4  = idx & 31;
            float4 v = *(const float4*)(W + (size_t)(kt + kk) * D + c4 * 4);
            *(float4*)&ws[kk][c4 * 4] = v;
        }
        __syncthreads();
#pragma unroll
        for (int k = 0; k < BK; ++k) {
            float4 wv = *(const float4*)&ws[k][tx * 4];
            float4 xa = *(const float4*)&xs[k][ty * 8];
            float4 xb = *(const float4*)&xs[k][ty * 8 + 4];
            float xv[8] = {xa.x, xa.y, xa.z, xa.w, xb.x, xb.y, xb.z, xb.w};
#pragma unroll
            for (int i = 0; i < 8; ++i) {
                acc[i][0] += xv[i] * wv.x;
                acc[i][1] += xv[i] * wv.y;
                acc[i][2] += xv[i] * wv.z;
                acc[i][3] += xv[i] * wv.w;
            }
        }
    }
#pragma unroll
    for (int i = 0; i < 8; ++i) {
        int grow = row0 + ty * 8 + i;
        if (grow < nrows) {
            union { ushort4 u; __hip_bfloat16 h[4]; } pk;
            pk.h[0] = __float2bfloat16(acc[i][0]);
            pk.h[1] = __float2bfloat16(acc[i][1]);
            pk.h[2] = __float2bfloat16(acc[i][2]);
            pk.h[3] = __float2bfloat16(acc[i][3]);
            *(ushort4*)((unsigned short*)y + (size_t)grow * D + tx * 4) = pk.u;
        }
    }
}

// ---------------- gather-side aggregate: one 32-lane group per dst node ----------------
// MODE 0: out = acc*rs_in   1: out += acc*rs_in   2: out = relu(out + acc*rs_in + b0+b1+b2)
template <int MODE>
__global__ __launch_bounds__(256) void agg_kernel(const __hip_bfloat16* __restrict__ y,
                                                  const int* __restrict__ src_sorted,
                                                  const int* __restrict__ off,
                                                  const float* __restrict__ rs_out,
                                                  const float* __restrict__ rs_in,
                                                  const float* __restrict__ b0,
                                                  const float* __restrict__ b1,
                                                  const float* __restrict__ b2,
                                                  float* __restrict__ out, int N, int E) {
    int gid  = blockIdx.x * blockDim.x + threadIdx.x;
    int node = gid >> 5;
    int lane = gid & 31;
    if (node >= N) return;
    int j0 = off[node];
    int j1 = (node == N - 1) ? E : off[node + 1];

    float a0 = 0.f, a1 = 0.f, a2 = 0.f, a3 = 0.f;
    for (int j = j0; j < j1; ++j) {
        int s = src_sorted[j];
        float c = rs_out[s];
        ushort4 u = *(const ushort4*)((const unsigned short*)y + (size_t)s * D + lane * 4);
        a0 += c * bf2f(u.x);
        a1 += c * bf2f(u.y);
        a2 += c * bf2f(u.z);
        a3 += c * bf2f(u.w);
    }
    float ri = rs_in[node];
    float4 o = make_float4(a0 * ri, a1 * ri, a2 * ri, a3 * ri);
    float* orow = out + (size_t)node * D + lane * 4;
    if (MODE == 0) {
        *(float4*)orow = o;
    } else {
        float4 p = *(const float4*)orow;
        o.x += p.x; o.y += p.y; o.z += p.z; o.w += p.w;
        if (MODE == 2) {
            int c0 = lane * 4;
            o.x = fmaxf(o.x + b0[c0 + 0] + b1[c0 + 0] + b2[c0 + 0], 0.f);
            o.y = fmaxf(o.y + b0[c0 + 1] + b1[c0 + 1] + b2[c0 + 1], 0.f);
            o.z = fmaxf(o.z + b0[c0 + 2] + b1[c0 + 2] + b2[c0 + 2], 0.f);
            o.w = fmaxf(o.w + b0[c0 + 3] + b1[c0 + 3] + b2[c0 + 3], 0.f);
        }
        *(float4*)orow = o;
    }
}

extern "C" void kernel_launch(void* const* d_in, const int* in_sizes, int n_in,
                              void* d_out, int out_size, void* d_ws, size_t ws_size,
                              hipStream_t stream) {
    const float* x = (const float*)d_in[0];
    const float* W[3]   = {(const float*)d_in[1], (const float*)d_in[5], (const float*)d_in[9]};
    const float* b[3]   = {(const float*)d_in[2], (const float*)d_in[6], (const float*)d_in[10]};
    const int*   src[3] = {(const int*)d_in[3],   (const int*)d_in[7],   (const int*)d_in[11]};
    const int*   dst[3] = {(const int*)d_in[4],   (const int*)d_in[8],   (const int*)d_in[12]};

    const int N = in_sizes[0] / D;
    const int E = in_sizes[3];
    float* out = (float*)d_out;

    // workspace: [cnt 6N int][cursor 3N int][rs 6N f][off 3N int][aux 3*512 int][srcs 3E int][y N*D bf16]
    char* p = (char*)d_ws;
    int* cnt    = (int*)p;               p += (size_t)6 * N * 4;   // out0,in0,out1,in1,out2,in2
    int* cursor = (int*)p;               p += (size_t)3 * N * 4;
    float* rs   = (float*)p;             p += (size_t)6 * N * 4;   // same order as cnt
    int* off    = (int*)p;               p += (size_t)3 * N * 4;
    int* aux    = (int*)p;               p += (size_t)3 * 512 * 4;
    int* srcs   = (int*)p;               p += (size_t)3 * E * 4;
    p = (char*)(((uintptr_t)p + 15) & ~(uintptr_t)15);
    __hip_bfloat16* y = (__hip_bfloat16*)p;

    // zero cnt + cursor (adjacent, 9N ints)
    hipMemsetAsync(cnt, 0, (size_t)9 * N * 4, stream);

    const int eb  = (E + 255) / 256;
    const int nb  = (N + 255) / 256;          // 391 (<= 512 for scan_aux)
    for (int r = 0; r < 3; ++r)
        degree_kernel<<<eb, 256, 0, stream>>>(src[r], dst[r], cnt + (size_t)(2 * r) * N,
                                              cnt + (size_t)(2 * r + 1) * N, E);
    rsqrt_kernel<<<(6 * N + 255) / 256, 256, 0, stream>>>(cnt, rs, 6 * N);

    for (int r = 0; r < 3; ++r) {
        int* cnt_in = cnt + (size_t)(2 * r + 1) * N;
        int* off_r  = off + (size_t)r * N;
        int* aux_r  = aux + (size_t)r * 512;
        scan_block<<<nb, 256, 0, stream>>>(cnt_in, off_r, aux_r, N);
        scan_aux<<<1, 512, 0, stream>>>(aux_r, nb);
        scan_add<<<nb, 256, 0, stream>>>(off_r, aux_r, N);
        fill_kernel<<<eb, 256, 0, stream>>>(src[r], dst[r], off_r, cursor + (size_t)r * N,
                                            srcs + (size_t)r * E, E);
    }

    const int gblocks = (N + BM - 1) / BM;
    const int ablocks = ((size_t)N * 32 + 255) / 256;
    for (int r = 0; r < 3; ++r) {
        gemm_kernel<<<gblocks, 256, 0, stream>>>(x, W[r], y, N);
        const int* off_r = off + (size_t)r * N;
        const int* src_r = srcs + (size_t)r * E;
        const float* ro = rs + (size_t)(2 * r) * N;
        const float* ri = rs + (size_t)(2 * r + 1) * N;
        if (r == 0)
            agg_kernel<0><<<ablocks, 256, 0, stream>>>(y, src_r, off_r, ro, ri,
                                                       b[0], b[1], b[2], out, N, E);
        else if (r == 1)
            agg_kernel<1><<<ablocks, 256, 0, stream>>>(y, src_r, off_r, ro, ri,
                                                       b[0], b[1], b[2], out, N, E);
        else
            agg_kernel<2><<<ablocks, 256, 0, stream>>>(y, src_r, off_r, ro, ri,
                                                       b[0], b[1], b[2], out, N, E);
    }
}